// Round 2
// 336.338 us; speedup vs baseline: 1.0060x; 1.0060x over previous
//
#include <hip/hip_runtime.h>
#include <hip/hip_bf16.h>

// BlockSparseLinear: y = x @ W^T + b
// Round 4 (resubmit — round-1 bench was an infra failure, no data): double-
// buffered LDS with prefetch-before-compute (guide §5.5 T3 "minimum 2-phase").
// Per kb: issue next tile's global_load_lds DMA, then compute current tile,
// then ONE barrier. The prefetch overlaps the whole MFMA+ds_read phase, so the
// barrier's vmcnt drain pays only residual latency (previous structure exposed
// full global->LDS latency 16x per block).
// Retained from round 3: 16B global_load_lds DMA, XOR chunk swizzle
// (bank-conflict-free, measured 0), bf16 pre-convert pass, XCD swizzle.

#define NTHREADS 256
#define TM 256          // tokens per workgroup tile
#define KNZ 16          // nonzero col-blocks per row-block

typedef __attribute__((ext_vector_type(8))) short short8;    // bf16 x8 (16 B)
typedef __attribute__((ext_vector_type(4))) float floatx4;

__device__ __forceinline__ unsigned short f2bf(float f) {
    unsigned u = __float_as_uint(f);
    u += 0x7fffu + ((u >> 16) & 1u);
    return (unsigned short)(u >> 16);
}

// async 16B global -> LDS DMA; lds base must be wave-uniform, dest = base + lane*16
__device__ __forceinline__ void gl_lds_16(const void* g, void* l) {
    __builtin_amdgcn_global_load_lds(
        (const __attribute__((address_space(1))) unsigned int*)g,
        (__attribute__((address_space(3))) unsigned int*)l,
        16, 0, 0);
}

// ---- Kernel 1: fp32 -> bf16 conversion (x then w) ----
__global__ __launch_bounds__(NTHREADS)
void cvt_kernel(const float* __restrict__ x, const float* __restrict__ w,
                unsigned short* __restrict__ xb, unsigned short* __restrict__ wb,
                int n_x8, int n_w8)
{
    int g = blockIdx.x * NTHREADS + threadIdx.x;
    const float* src;
    unsigned short* dst;
    if (g < n_x8) { src = x + (size_t)g * 8; dst = xb + (size_t)g * 8; }
    else {
        int h = g - n_x8;
        if (h >= n_w8) return;
        src = w + (size_t)h * 8; dst = wb + (size_t)h * 8;
    }
    floatx4 v0 = *(const floatx4*)(src);
    floatx4 v1 = *(const floatx4*)(src + 4);
    union { ushort4 u4[2]; short8 s8; } p;
    p.u4[0].x = f2bf(v0.x); p.u4[0].y = f2bf(v0.y);
    p.u4[0].z = f2bf(v0.z); p.u4[0].w = f2bf(v0.w);
    p.u4[1].x = f2bf(v1.x); p.u4[1].y = f2bf(v1.y);
    p.u4[1].z = f2bf(v1.z); p.u4[1].w = f2bf(v1.w);
    *(short8*)dst = p.s8;
}

// ---- Kernel 2: bf16 MFMA GEMM, double-buffered async LDS staging ----
__global__ __launch_bounds__(NTHREADS)
void bsl_mfma_bf16_kernel(const unsigned short* __restrict__ xb,
                          const unsigned short* __restrict__ wb,
                          const float* __restrict__ bias,
                          const int* __restrict__ col_idx,
                          float* __restrict__ out,
                          int n_tiles)
{
    // Unpadded (DMA dest = wave-uniform base + lane*16); chunk position is
    // XOR-swizzled via the per-lane GLOBAL source address. Double-buffered.
    __shared__ unsigned short Xs[2][TM * 64];   // 2 x 32 KB
    __shared__ unsigned short Ws[2][64 * 64];   // 2 x 8 KB   -> 80 KB total

    // XCD swizzle: give each XCD whole token-tile groups so its x-slab stays
    // hot in its private L2.
    int id = blockIdx.x;
    int rb, tt;
    if (n_tiles == 32) {
        int xcd  = id & 7;
        int slot = id >> 3;          // 0..255 within XCD
        rb = slot & 63;
        tt = xcd * 4 + (slot >> 6);
    } else {
        rb = id & 63;
        tt = id >> 6;
    }

    const int tid  = threadIdx.x;
    const int lane = tid & 63;
    const int wv   = tid >> 6;
    const int l15  = lane & 15;
    const int l4   = lane >> 4;
    const int tok0 = tt * TM;
    const int lr   = lane >> 3;      // 0..7: row within a DMA wave-load
    const int lc   = lane & 7;       // 0..7: swizzled chunk slot

    floatx4 acc[4][4];
    #pragma unroll
    for (int i = 0; i < 4; ++i)
        #pragma unroll
        for (int j = 0; j < 4; ++j)
            acc[i][j] = (floatx4){0.f, 0.f, 0.f, 0.f};

    // Issue the 10 DMA wave-loads for col-block kb into buffer buf.
    auto stage = [&](int buf, int kb) {
        const int nz = rb * KNZ + kb;
        const int cb = col_idx[nz];                       // uniform -> s_load
        const unsigned short* xsrc = xb + (size_t)tok0 * 4096 + (size_t)cb * 64;
        const unsigned short* wsrc = wb + (size_t)nz * 4096;
        unsigned short* xd = &Xs[buf][0];
        unsigned short* wd = &Ws[buf][0];
        // W first (only 2 loads; gets W in flight earliest)
        #pragma unroll
        for (int j = 0; j < 2; ++j) {
            int L   = wv * 2 + j;
            int row = L * 8 + lr;
            int c8  = lc ^ (row & 7);
            gl_lds_16(wsrc + row * 64 + c8 * 8, wd + L * 512);
        }
        // X: 256 rows x 8 chunks = 32 wave-loads of 1 KB; wave wv does 8.
        // LDS slot s = L*64 + lane holds global chunk c8 = (lane&7) ^ (row&7).
        #pragma unroll
        for (int j = 0; j < 8; ++j) {
            int L   = wv * 8 + j;
            int row = L * 8 + lr;
            int c8  = lc ^ (row & 7);
            gl_lds_16(xsrc + (size_t)row * 4096 + c8 * 8, xd + L * 512);
        }
    };

    // Compute K=64 (two k-steps of 32) from buffer buf. Chunk c8k = ks*4 + l4
    // lives at swizzled offset (c8k ^ (row&7))*8; row&7 == l15&7 for all frags.
    auto compute = [&](int buf) {
        const unsigned short* Xc = &Xs[buf][0];
        const unsigned short* Wc = &Ws[buf][0];
        #pragma unroll
        for (int ks = 0; ks < 2; ++ks) {
            const int sw8 = ((ks * 4 + l4) ^ (l15 & 7)) * 8;
            short8 a[4], b[4];
            #pragma unroll
            for (int mt = 0; mt < 4; ++mt)
                a[mt] = *(const short8*)&Xc[(wv * 64 + mt * 16 + l15) * 64 + sw8];
            #pragma unroll
            for (int nt = 0; nt < 4; ++nt)
                b[nt] = *(const short8*)&Wc[(nt * 16 + l15) * 64 + sw8];
            #pragma unroll
            for (int mt = 0; mt < 4; ++mt)
                #pragma unroll
                for (int nt = 0; nt < 4; ++nt)
                    acc[mt][nt] = __builtin_amdgcn_mfma_f32_16x16x32_bf16(
                        a[mt], b[nt], acc[mt][nt], 0, 0, 0);
        }
    };

    // Prologue: fill buffer 0, drain, barrier.
    stage(0, 0);
    __syncthreads();

    // 2-phase pipeline, unrolled x2 so buffer index is compile-time.
    // Safety: buf being overwritten by stage() was last ds_read one iteration
    // ago; the __syncthreads() at the end of that iteration (lgkmcnt(0) drain)
    // guarantees those reads completed in all waves. The __syncthreads() after
    // each compute drains vmcnt(0), making this iteration's prefetch visible —
    // but that prefetch had the whole compute phase to land.
    for (int kb = 0; kb < KNZ; kb += 2) {
        stage(1, kb + 1);            // kb+1 <= 15 always (KNZ even)
        compute(0);
        __syncthreads();
        if (kb + 2 < KNZ) stage(0, kb + 2);
        compute(1);
        __syncthreads();
    }

    // Epilogue: C/D layout col = lane&15, row = (lane>>4)*4 + reg.
    const int ocol0 = rb * 64;
    #pragma unroll
    for (int nt = 0; nt < 4; ++nt) {
        const int col = ocol0 + nt * 16 + l15;
        const float bv = bias[col];
        #pragma unroll
        for (int mt = 0; mt < 4; ++mt) {
            const size_t trow = (size_t)tok0 + wv * 64 + mt * 16 + l4 * 4;
            float* op = out + trow * 4096 + col;
            #pragma unroll
            for (int r = 0; r < 4; ++r)
                op[(size_t)r * 4096] = acc[mt][nt][r] + bv;
        }
    }
}

// ---- Fallback (fp32 direct) if ws too small ----
#define XS_LD 72
#define WS_LD 72
__global__ __launch_bounds__(NTHREADS)
void bsl_mfma_f32_kernel(const float* __restrict__ x,
                         const float* __restrict__ w,
                         const float* __restrict__ bias,
                         const int* __restrict__ col_idx,
                         float* __restrict__ out)
{
    __shared__ unsigned short Xs[TM * XS_LD];
    __shared__ unsigned short Ws[64 * WS_LD];
    const int rb = blockIdx.x, tt = blockIdx.y;
    const int tid = threadIdx.x, lane = tid & 63, wv = tid >> 6;
    const int l15 = lane & 15, l4 = lane >> 4, tok0 = tt * TM;
    floatx4 acc[4][4];
    #pragma unroll
    for (int i = 0; i < 4; ++i)
        #pragma unroll
        for (int j = 0; j < 4; ++j) acc[i][j] = (floatx4){0.f,0.f,0.f,0.f};
    for (int kb = 0; kb < KNZ; ++kb) {
        const int nz = rb * KNZ + kb;
        const int cb = col_idx[nz];
        const float* xsrc = x + (size_t)tok0 * 4096 + (size_t)cb * 64;
        const float* wsrc = w + (size_t)nz * 4096;
        __syncthreads();
        #pragma unroll
        for (int i = 0; i < 16; ++i) {
            int f = i * NTHREADS + tid, row = f >> 4, c4 = f & 15;
            floatx4 v = *(const floatx4*)(xsrc + (size_t)row * 4096 + c4 * 4);
            ushort4 p; p.x=f2bf(v.x); p.y=f2bf(v.y); p.z=f2bf(v.z); p.w=f2bf(v.w);
            *(ushort4*)&Xs[row * XS_LD + c4 * 4] = p;
        }
        #pragma unroll
        for (int i = 0; i < 4; ++i) {
            int f = i * NTHREADS + tid, row = f >> 4, c4 = f & 15;
            floatx4 v = *(const floatx4*)(wsrc + row * 64 + c4 * 4);
            ushort4 p; p.x=f2bf(v.x); p.y=f2bf(v.y); p.z=f2bf(v.z); p.w=f2bf(v.w);
            *(ushort4*)&Ws[row * WS_LD + c4 * 4] = p;
        }
        __syncthreads();
        #pragma unroll
        for (int ks = 0; ks < 2; ++ks) {
            const int k0 = ks * 32 + l4 * 8;
            short8 a[4], b[4];
            #pragma unroll
            for (int mt = 0; mt < 4; ++mt)
                a[mt] = *(const short8*)&Xs[(wv*64 + mt*16 + l15) * XS_LD + k0];
            #pragma unroll
            for (int nt = 0; nt < 4; ++nt)
                b[nt] = *(const short8*)&Ws[(nt*16 + l15) * WS_LD + k0];
            #pragma unroll
            for (int mt = 0; mt < 4; ++mt)
                #pragma unroll
                for (int nt = 0; nt < 4; ++nt)
                    acc[mt][nt] = __builtin_amdgcn_mfma_f32_16x16x32_bf16(
                        a[mt], b[nt], acc[mt][nt], 0, 0, 0);
        }
    }
    const int ocol0 = rb * 64;
    #pragma unroll
    for (int nt = 0; nt < 4; ++nt) {
        const int col = ocol0 + nt * 16 + l15;
        const float bv = bias[col];
        #pragma unroll
        for (int mt = 0; mt < 4; ++mt) {
            const size_t trow = (size_t)tok0 + wv * 64 + mt * 16 + l4 * 4;
            float* op = out + trow * 4096 + col;
            #pragma unroll
            for (int r = 0; r < 4; ++r)
                op[(size_t)r * 4096] = acc[mt][nt][r] + bv;
        }
    }
}

extern "C" void kernel_launch(void* const* d_in, const int* in_sizes, int n_in,
                              void* d_out, int out_size, void* d_ws, size_t ws_size,
                              hipStream_t stream) {
    const float* x       = (const float*)d_in[0];
    const float* w       = (const float*)d_in[1];
    const float* bias    = (const float*)d_in[2];
    const int*   col_idx = (const int*)d_in[4];
    float*       out     = (float*)d_out;

    const int n_x = in_sizes[0];
    const int n_w = in_sizes[1];
    const int n_tok = n_x / 4096;
    const size_t need = (size_t)(n_x + n_w) * 2;

    if (ws_size >= need) {
        unsigned short* xb = (unsigned short*)d_ws;
        unsigned short* wb = xb + n_x;
        int n_x8 = n_x / 8, n_w8 = n_w / 8;
        int total = n_x8 + n_w8;
        cvt_kernel<<<(total + NTHREADS - 1) / NTHREADS, NTHREADS, 0, stream>>>(
            x, w, xb, wb, n_x8, n_w8);
        int n_tiles = n_tok / TM;
        bsl_mfma_bf16_kernel<<<64 * n_tiles, NTHREADS, 0, stream>>>(
            xb, wb, bias, col_idx, out, n_tiles);
    } else {
        dim3 grid(64, n_tok / TM);
        bsl_mfma_f32_kernel<<<grid, NTHREADS, 0, stream>>>(x, w, bias, col_idx, out);
    }
}

// Round 3
// 325.566 us; speedup vs baseline: 1.0393x; 1.0331x over previous
//
#include <hip/hip_runtime.h>
#include <hip/hip_bf16.h>

// BlockSparseLinear: y = x @ W^T + b
// Round 5: revert double-buffering (measured neutral-to-negative, confirming
// guide m99/m100: source-level dbuf cannot beat the barrier's vmcnt(0) drain).
// Counters showed the real deficit is TLP: occupancy ~20% (= 1.6 waves/SIMD).
// This round: TM=512 tokens per block with 512 threads (8 waves), single
// 72 KB LDS buffer -> 2 blocks/CU -> 16 waves/CU (50% ceiling, was ~20%).
// Per-wave inner code identical to round 3 (64x64 out tile, 4x4 acc, same
// ds_read/MFMA mix); intensity 51->57 FLOP/staged-byte (W amortized 2x).
// Retained: 16B global_load_lds DMA, XOR chunk swizzle (0 conflicts),
// bf16 pre-convert pass, XCD swizzle (generalized to n_tiles=16).

#define NTHREADS 512    // 8 waves
#define TM 512          // tokens per workgroup tile
#define KNZ 16          // nonzero col-blocks per row-block

typedef __attribute__((ext_vector_type(8))) short short8;    // bf16 x8 (16 B)
typedef __attribute__((ext_vector_type(4))) float floatx4;

__device__ __forceinline__ unsigned short f2bf(float f) {
    unsigned u = __float_as_uint(f);
    u += 0x7fffu + ((u >> 16) & 1u);
    return (unsigned short)(u >> 16);
}

// async 16B global -> LDS DMA; lds base must be wave-uniform, dest = base + lane*16
__device__ __forceinline__ void gl_lds_16(const void* g, void* l) {
    __builtin_amdgcn_global_load_lds(
        (const __attribute__((address_space(1))) unsigned int*)g,
        (__attribute__((address_space(3))) unsigned int*)l,
        16, 0, 0);
}

// ---- Kernel 1: fp32 -> bf16 conversion (x then w) ----
#define CVT_THREADS 256
__global__ __launch_bounds__(CVT_THREADS)
void cvt_kernel(const float* __restrict__ x, const float* __restrict__ w,
                unsigned short* __restrict__ xb, unsigned short* __restrict__ wb,
                int n_x8, int n_w8)
{
    int g = blockIdx.x * CVT_THREADS + threadIdx.x;
    const float* src;
    unsigned short* dst;
    if (g < n_x8) { src = x + (size_t)g * 8; dst = xb + (size_t)g * 8; }
    else {
        int h = g - n_x8;
        if (h >= n_w8) return;
        src = w + (size_t)h * 8; dst = wb + (size_t)h * 8;
    }
    floatx4 v0 = *(const floatx4*)(src);
    floatx4 v1 = *(const floatx4*)(src + 4);
    union { ushort4 u4[2]; short8 s8; } p;
    p.u4[0].x = f2bf(v0.x); p.u4[0].y = f2bf(v0.y);
    p.u4[0].z = f2bf(v0.z); p.u4[0].w = f2bf(v0.w);
    p.u4[1].x = f2bf(v1.x); p.u4[1].y = f2bf(v1.y);
    p.u4[1].z = f2bf(v1.z); p.u4[1].w = f2bf(v1.w);
    *(short8*)dst = p.s8;
}

// ---- Kernel 2: bf16 MFMA GEMM, 8-wave blocks, single-buffered staging ----
__global__ __launch_bounds__(NTHREADS, 4)   // 4 waves/SIMD -> 2 blocks/CU, VGPR<=128
void bsl_mfma_bf16_kernel(const unsigned short* __restrict__ xb,
                          const unsigned short* __restrict__ wb,
                          const float* __restrict__ bias,
                          const int* __restrict__ col_idx,
                          float* __restrict__ out,
                          int n_tiles)
{
    // Unpadded (DMA dest = wave-uniform base + lane*16); chunk position is
    // XOR-swizzled via the per-lane GLOBAL source address.
    __shared__ unsigned short Xs[TM * 64];   // 64 KB
    __shared__ unsigned short Ws[64 * 64];   // 8 KB   -> 72 KB total, 2 blk/CU

    // XCD swizzle: consecutive ids round-robin across 8 XCDs; give each XCD
    // whole token-tile groups so its 4 MB x-slab stays hot in its private L2.
    int id = blockIdx.x;
    int rb, tt;
    if ((n_tiles & 7) == 0) {
        int xcd  = id & 7;
        int slot = id >> 3;           // 0 .. 64*tpx-1 within XCD
        int tpx  = n_tiles >> 3;      // token tiles per XCD
        rb = slot & 63;
        tt = xcd * tpx + (slot >> 6);
    } else {
        rb = id & 63;
        tt = id >> 6;
    }

    const int tid  = threadIdx.x;
    const int lane = tid & 63;
    const int wv   = tid >> 6;       // 0..7
    const int l15  = lane & 15;
    const int l4   = lane >> 4;
    const int tok0 = tt * TM;
    const int lr   = lane >> 3;      // 0..7: row within a DMA wave-load
    const int lc   = lane & 7;       // 0..7: swizzled chunk slot

    floatx4 acc[4][4];
    #pragma unroll
    for (int i = 0; i < 4; ++i)
        #pragma unroll
        for (int j = 0; j < 4; ++j)
            acc[i][j] = (floatx4){0.f, 0.f, 0.f, 0.f};

    for (int kb = 0; kb < KNZ; ++kb) {
        const int nz = rb * KNZ + kb;
        const int cb = col_idx[nz];                       // uniform -> s_load
        const unsigned short* xsrc = xb + (size_t)tok0 * 4096 + (size_t)cb * 64;
        const unsigned short* wsrc = wb + (size_t)nz * 4096;

        __syncthreads();   // previous compute done before overwriting LDS

        // W: 64 rows x 8 chunks = 8 wave-loads of 1 KB; wave wv does 1.
        {
            int row = wv * 8 + lr;
            int c8  = lc ^ (row & 7);
            gl_lds_16(wsrc + row * 64 + c8 * 8, &Ws[wv * 512]);
        }
        // X: 512 rows x 8 chunks = 64 wave-loads of 1 KB; wave wv does 8.
        // LDS slot s = L*64 + lane holds global chunk c8 = (lane&7) ^ (row&7).
        #pragma unroll
        for (int j = 0; j < 8; ++j) {
            int L   = wv * 8 + j;
            int row = L * 8 + lr;
            int c8  = lc ^ (row & 7);
            gl_lds_16(xsrc + (size_t)row * 4096 + c8 * 8, &Xs[L * 512]);
        }

        __syncthreads();   // drains vmcnt -> DMA complete, staging visible

        // Compute: K=64 as two k-steps of 32. Chunk c8k = ks*4 + l4 lives at
        // swizzled offset (c8k ^ (row&7))*8; row&7 == l15&7 for all frags.
        #pragma unroll
        for (int ks = 0; ks < 2; ++ks) {
            const int sw8 = ((ks * 4 + l4) ^ (l15 & 7)) * 8;
            short8 a[4], b[4];
            #pragma unroll
            for (int mt = 0; mt < 4; ++mt)
                a[mt] = *(const short8*)&Xs[(wv * 64 + mt * 16 + l15) * 64 + sw8];
            #pragma unroll
            for (int nt = 0; nt < 4; ++nt)
                b[nt] = *(const short8*)&Ws[(nt * 16 + l15) * 64 + sw8];
            #pragma unroll
            for (int mt = 0; mt < 4; ++mt)
                #pragma unroll
                for (int nt = 0; nt < 4; ++nt)
                    acc[mt][nt] = __builtin_amdgcn_mfma_f32_16x16x32_bf16(
                        a[mt], b[nt], acc[mt][nt], 0, 0, 0);
        }
    }

    // Epilogue: C/D layout col = lane&15, row = (lane>>4)*4 + reg.
    const int ocol0 = rb * 64;
    #pragma unroll
    for (int nt = 0; nt < 4; ++nt) {
        const int col = ocol0 + nt * 16 + l15;
        const float bv = bias[col];
        #pragma unroll
        for (int mt = 0; mt < 4; ++mt) {
            const size_t trow = (size_t)tok0 + wv * 64 + mt * 16 + l4 * 4;
            float* op = out + trow * 4096 + col;
            #pragma unroll
            for (int r = 0; r < 4; ++r)
                op[(size_t)r * 4096] = acc[mt][nt][r] + bv;
        }
    }
}

// ---- Fallback (fp32 direct) if ws too small ---- (256 threads, TM=256)
#define TMF 256
#define NTF 256
#define XS_LD 72
#define WS_LD 72
__global__ __launch_bounds__(NTF)
void bsl_mfma_f32_kernel(const float* __restrict__ x,
                         const float* __restrict__ w,
                         const float* __restrict__ bias,
                         const int* __restrict__ col_idx,
                         float* __restrict__ out)
{
    __shared__ unsigned short Xs[TMF * XS_LD];
    __shared__ unsigned short Ws[64 * WS_LD];
    const int rb = blockIdx.x, tt = blockIdx.y;
    const int tid = threadIdx.x, lane = tid & 63, wv = tid >> 6;
    const int l15 = lane & 15, l4 = lane >> 4, tok0 = tt * TMF;
    floatx4 acc[4][4];
    #pragma unroll
    for (int i = 0; i < 4; ++i)
        #pragma unroll
        for (int j = 0; j < 4; ++j) acc[i][j] = (floatx4){0.f,0.f,0.f,0.f};
    for (int kb = 0; kb < KNZ; ++kb) {
        const int nz = rb * KNZ + kb;
        const int cb = col_idx[nz];
        const float* xsrc = x + (size_t)tok0 * 4096 + (size_t)cb * 64;
        const float* wsrc = w + (size_t)nz * 4096;
        __syncthreads();
        #pragma unroll
        for (int i = 0; i < 16; ++i) {
            int f = i * NTF + tid, row = f >> 4, c4 = f & 15;
            floatx4 v = *(const floatx4*)(xsrc + (size_t)row * 4096 + c4 * 4);
            ushort4 p; p.x=f2bf(v.x); p.y=f2bf(v.y); p.z=f2bf(v.z); p.w=f2bf(v.w);
            *(ushort4*)&Xs[row * XS_LD + c4 * 4] = p;
        }
        #pragma unroll
        for (int i = 0; i < 4; ++i) {
            int f = i * NTF + tid, row = f >> 4, c4 = f & 15;
            floatx4 v = *(const floatx4*)(wsrc + row * 64 + c4 * 4);
            ushort4 p; p.x=f2bf(v.x); p.y=f2bf(v.y); p.z=f2bf(v.z); p.w=f2bf(v.w);
            *(ushort4*)&Ws[row * WS_LD + c4 * 4] = p;
        }
        __syncthreads();
        #pragma unroll
        for (int ks = 0; ks < 2; ++ks) {
            const int k0 = ks * 32 + l4 * 8;
            short8 a[4], b[4];
            #pragma unroll
            for (int mt = 0; mt < 4; ++mt)
                a[mt] = *(const short8*)&Xs[(wv*64 + mt*16 + l15) * XS_LD + k0];
            #pragma unroll
            for (int nt = 0; nt < 4; ++nt)
                b[nt] = *(const short8*)&Ws[(nt*16 + l15) * WS_LD + k0];
            #pragma unroll
            for (int mt = 0; mt < 4; ++mt)
                #pragma unroll
                for (int nt = 0; nt < 4; ++nt)
                    acc[mt][nt] = __builtin_amdgcn_mfma_f32_16x16x32_bf16(
                        a[mt], b[nt], acc[mt][nt], 0, 0, 0);
        }
    }
    const int ocol0 = rb * 64;
    #pragma unroll
    for (int nt = 0; nt < 4; ++nt) {
        const int col = ocol0 + nt * 16 + l15;
        const float bv = bias[col];
        #pragma unroll
        for (int mt = 0; mt < 4; ++mt) {
            const size_t trow = (size_t)tok0 + wv * 64 + mt * 16 + l4 * 4;
            float* op = out + trow * 4096 + col;
            #pragma unroll
            for (int r = 0; r < 4; ++r)
                op[(size_t)r * 4096] = acc[mt][nt][r] + bv;
        }
    }
}

extern "C" void kernel_launch(void* const* d_in, const int* in_sizes, int n_in,
                              void* d_out, int out_size, void* d_ws, size_t ws_size,
                              hipStream_t stream) {
    const float* x       = (const float*)d_in[0];
    const float* w       = (const float*)d_in[1];
    const float* bias    = (const float*)d_in[2];
    const int*   col_idx = (const int*)d_in[4];
    float*       out     = (float*)d_out;

    const int n_x = in_sizes[0];
    const int n_w = in_sizes[1];
    const int n_tok = n_x / 4096;
    const size_t need = (size_t)(n_x + n_w) * 2;

    if (ws_size >= need && (n_tok % TM) == 0) {
        unsigned short* xb = (unsigned short*)d_ws;
        unsigned short* wb = xb + n_x;
        int n_x8 = n_x / 8, n_w8 = n_w / 8;
        int total = n_x8 + n_w8;
        cvt_kernel<<<(total + CVT_THREADS - 1) / CVT_THREADS, CVT_THREADS, 0, stream>>>(
            x, w, xb, wb, n_x8, n_w8);
        int n_tiles = n_tok / TM;
        bsl_mfma_bf16_kernel<<<64 * n_tiles, NTHREADS, 0, stream>>>(
            xb, wb, bias, col_idx, out, n_tiles);
    } else {
        dim3 grid(64, n_tok / TMF);
        bsl_mfma_f32_kernel<<<grid, NTF, 0, stream>>>(x, w, bias, col_idx, out);
    }
}